// Round 1
// baseline (641.630 us; speedup 1.0000x reference)
//
#include <hip/hip_runtime.h>
#include <hip/hip_bf16.h>

#define N_NODES 100000
#define N_EDGES 1600000
#define D 128

// ---------------- CSR build ----------------

__global__ void k_zero(int* __restrict__ p, int n) {
    int i = blockIdx.x * 256 + threadIdx.x;
    if (i < n) p[i] = 0;
}

__global__ void k_hist(const int* __restrict__ dst, int* __restrict__ deg, int E) {
    int i = blockIdx.x * 256 + threadIdx.x;
    if (i < E) atomicAdd(&deg[dst[i]], 1);
}

// Per-chunk (1024 elements) exclusive scan; chunk totals -> partials.
__global__ void k_scan_blocks(const int* __restrict__ deg, int* __restrict__ rowptr,
                              int* __restrict__ partials, int n) {
    __shared__ int tmp[256];
    int chunk = blockIdx.x, tid = threadIdx.x;
    int base = chunk * 1024 + tid * 4;
    int v[4];
    int s = 0;
    for (int j = 0; j < 4; j++) {
        int idx = base + j;
        v[j] = (idx < n) ? deg[idx] : 0;
        s += v[j];
    }
    tmp[tid] = s;
    __syncthreads();
    for (int off = 1; off < 256; off <<= 1) {
        int t = 0;
        if (tid >= off) t = tmp[tid - off];
        __syncthreads();
        tmp[tid] += t;
        __syncthreads();
    }
    int excl = tmp[tid] - s;   // exclusive prefix of this thread's 4-group
    int run = excl;
    for (int j = 0; j < 4; j++) {
        int idx = base + j;
        if (idx < n) rowptr[idx] = run;
        run += v[j];
    }
    if (tid == 255) partials[chunk] = tmp[255];  // chunk total
}

// Exclusive scan of chunk totals (m <= 256), single block.
__global__ void k_scan_partials(int* __restrict__ partials, int m) {
    __shared__ int tmp[256];
    int tid = threadIdx.x;
    int s = (tid < m) ? partials[tid] : 0;
    tmp[tid] = s;
    __syncthreads();
    for (int off = 1; off < 256; off <<= 1) {
        int t = 0;
        if (tid >= off) t = tmp[tid - off];
        __syncthreads();
        tmp[tid] += t;
        __syncthreads();
    }
    if (tid < m) partials[tid] = tmp[tid] - s;
}

__global__ void k_scan_add(int* __restrict__ rowptr, const int* __restrict__ partials,
                           int* __restrict__ cursor, int n, int E) {
    int i = blockIdx.x * 256 + threadIdx.x;
    if (i < n) {
        int r = rowptr[i] + partials[i / 1024];
        rowptr[i] = r;
        cursor[i] = r;
    }
    if (i == n) rowptr[n] = E;
}

__global__ void k_scatter(const int* __restrict__ src, const int* __restrict__ dst,
                          const float* __restrict__ ew, int* __restrict__ cursor,
                          int* __restrict__ srcs, float* __restrict__ wss, int E) {
    int i = blockIdx.x * 256 + threadIdx.x;
    if (i < E) {
        int d = dst[i];
        int p = atomicAdd(&cursor[d], 1);
        srcs[p] = src[i];
        wss[p]  = ew[i];
    }
}

// ---------------- GEMM: H[n x 128] = X[n x 128] @ W[128 x 128] ----------------
// Block: 256 threads; tile 64 rows x 64 cols (blockIdx.y selects col half).
// LDS: W-half (128k x 64c, 32KB) + X-tile transposed (128k x 64r, 32KB) = 64KB.
__global__ __launch_bounds__(256) void k_gemm(const float* __restrict__ X,
                                              const float* __restrict__ W,
                                              float* __restrict__ H, int n) {
    __shared__ float sW[128][64];   // sW[k][c]
    __shared__ float sX[128][64];   // sX[k][r]  (transposed x tile)
    int rows0 = blockIdx.x * 64;
    int cols0 = blockIdx.y * 64;
    int tid = threadIdx.x;

    // Stage W half: 8192 floats = 2048 float4, 8 per thread, coalesced per k-row.
    for (int i = 0; i < 8; i++) {
        int L4 = i * 256 + tid;           // float4 index
        int k  = L4 >> 4;                 // 16 float4 per 64-col row
        int c4 = L4 & 15;
        float4 w4 = *(const float4*)&W[k * 128 + cols0 + c4 * 4];
        *(float4*)&sW[k][c4 * 4] = w4;
    }
    // Stage X tile transposed: thread t -> row r=t/4, k-range (t%4)*32..+32.
    {
        int r  = tid >> 2;
        int kq = (tid & 3) * 32;
        int rg = rows0 + r;
        for (int j = 0; j < 8; j++) {
            float4 xv = make_float4(0.f, 0.f, 0.f, 0.f);
            if (rg < n) xv = *(const float4*)&X[(size_t)rg * 128 + kq + j * 4];
            int kk = kq + j * 4;
            sX[kk + 0][r] = xv.x;
            sX[kk + 1][r] = xv.y;
            sX[kk + 2][r] = xv.z;
            sX[kk + 3][r] = xv.w;
        }
    }
    __syncthreads();

    int tx = tid & 15;   // col group: cols tx*4..+3
    int ty = tid >> 4;   // row group: rows ty*4..+3
    float acc[4][4] = {};
    #pragma unroll 8
    for (int k = 0; k < 128; k++) {
        float4 a = *(const float4*)&sX[k][ty * 4];
        float4 b = *(const float4*)&sW[k][tx * 4];
        acc[0][0] += a.x * b.x; acc[0][1] += a.x * b.y; acc[0][2] += a.x * b.z; acc[0][3] += a.x * b.w;
        acc[1][0] += a.y * b.x; acc[1][1] += a.y * b.y; acc[1][2] += a.y * b.z; acc[1][3] += a.y * b.w;
        acc[2][0] += a.z * b.x; acc[2][1] += a.z * b.y; acc[2][2] += a.z * b.z; acc[2][3] += a.z * b.w;
        acc[3][0] += a.w * b.x; acc[3][1] += a.w * b.y; acc[3][2] += a.w * b.z; acc[3][3] += a.w * b.w;
    }
    for (int i = 0; i < 4; i++) {
        int row = rows0 + ty * 4 + i;
        if (row < n) {
            float4 o = make_float4(acc[i][0], acc[i][1], acc[i][2], acc[i][3]);
            *(float4*)&H[(size_t)row * 128 + cols0 + tx * 4] = o;
        }
    }
}

// ---------------- Aggregation: out[n] = tanh(sum_e w_e * H[src_e]) ----------------
// One wave per node; lane holds 2 columns (float2). CSR is dst-sorted.
__global__ __launch_bounds__(256) void k_agg(const float* __restrict__ H,
                                             const int* __restrict__ rowptr,
                                             const int* __restrict__ srcs,
                                             const float* __restrict__ wss,
                                             float* __restrict__ out, int n) {
    int wid  = (blockIdx.x * 256 + threadIdx.x) >> 6;
    int lane = threadIdx.x & 63;
    if (wid >= n) return;
    int e0 = rowptr[wid], e1 = rowptr[wid + 1];
    float a0 = 0.f, a1 = 0.f;
    for (int e = e0; e < e1; e++) {
        int   s = srcs[e];
        float w = wss[e];
        float2 v = *(const float2*)&H[(size_t)s * 128 + lane * 2];
        a0 += w * v.x;
        a1 += w * v.y;
    }
    float2 o = make_float2(tanhf(a0), tanhf(a1));
    *(float2*)&out[(size_t)wid * 128 + lane * 2] = o;
}

// ---------------- launch ----------------

extern "C" void kernel_launch(void* const* d_in, const int* in_sizes, int n_in,
                              void* d_out, int out_size, void* d_ws, size_t ws_size,
                              hipStream_t stream) {
    const float* x    = (const float*)d_in[0];
    const int*   esrc = (const int*)d_in[1];
    const int*   edst = (const int*)d_in[2];
    const float* ew   = (const float*)d_in[3];
    const float* W1   = (const float*)d_in[4];
    const float* W2   = (const float*)d_in[5];
    float* out = (float*)d_out;

    // Workspace layout (~65 MB):
    float* hbuf     = (float*)d_ws;                       // N*D f32  (51.2 MB)
    int*   deg      = (int*)(hbuf + (size_t)N_NODES * D); // N ints (reused as cursor)
    int*   rowptr   = deg + N_NODES;                      // N+1 ints
    int*   partials = rowptr + (N_NODES + 1);             // 256 ints
    int*   srcs     = partials + 256;                     // E ints
    float* wss      = (float*)(srcs + N_EDGES);           // E f32

    // --- CSR build (graph identical for both layers) ---
    k_zero<<<(N_NODES + 255) / 256, 256, 0, stream>>>(deg, N_NODES);
    k_hist<<<(N_EDGES + 255) / 256, 256, 0, stream>>>(edst, deg, N_EDGES);
    int nchunk = (N_NODES + 1023) / 1024;  // 98
    k_scan_blocks<<<nchunk, 256, 0, stream>>>(deg, rowptr, partials, N_NODES);
    k_scan_partials<<<1, 256, 0, stream>>>(partials, nchunk);
    k_scan_add<<<(N_NODES + 1 + 255) / 256, 256, 0, stream>>>(rowptr, partials, deg, N_NODES, N_EDGES);
    k_scatter<<<(N_EDGES + 255) / 256, 256, 0, stream>>>(esrc, edst, ew, deg, srcs, wss, N_EDGES);

    dim3 gg((N_NODES + 63) / 64, 2);
    int agg_blocks = (N_NODES * 64 + 255) / 256;  // one wave per node

    // --- layer 1 ---
    k_gemm<<<gg, 256, 0, stream>>>(x, W1, hbuf, N_NODES);
    k_agg<<<agg_blocks, 256, 0, stream>>>(hbuf, rowptr, srcs, wss, out, N_NODES);
    // --- layer 2 (reads layer-1 activations from d_out, then overwrites d_out) ---
    k_gemm<<<gg, 256, 0, stream>>>(out, W2, hbuf, N_NODES);
    k_agg<<<agg_blocks, 256, 0, stream>>>(hbuf, rowptr, srcs, wss, out, N_NODES);
}

// Round 4
// 445.387 us; speedup vs baseline: 1.4406x; 1.4406x over previous
//
#include <hip/hip_runtime.h>
#include <hip/hip_bf16.h>

#define N_NODES 100000
#define N_EDGES 1600000
#define D 128

typedef unsigned int  uint4n  __attribute__((ext_vector_type(4)));
typedef float         float4n __attribute__((ext_vector_type(4)));
typedef _Float16      half8n  __attribute__((ext_vector_type(8)));
typedef _Float16      half4n  __attribute__((ext_vector_type(4)));

// ---------------- CSR build ----------------

__global__ void k_zero(int* __restrict__ p, int n) {
    int i = blockIdx.x * 256 + threadIdx.x;
    if (i < n) p[i] = 0;
}

__global__ void k_hist(const int* __restrict__ dst, int* __restrict__ deg, int E) {
    int i = blockIdx.x * 256 + threadIdx.x;
    if (i < E) atomicAdd(&deg[dst[i]], 1);
}

__global__ void k_scan_blocks(const int* __restrict__ deg, int* __restrict__ rowptr,
                              int* __restrict__ partials, int n) {
    __shared__ int tmp[256];
    int chunk = blockIdx.x, tid = threadIdx.x;
    int base = chunk * 1024 + tid * 4;
    int v[4];
    int s = 0;
    for (int j = 0; j < 4; j++) {
        int idx = base + j;
        v[j] = (idx < n) ? deg[idx] : 0;
        s += v[j];
    }
    tmp[tid] = s;
    __syncthreads();
    for (int off = 1; off < 256; off <<= 1) {
        int t = 0;
        if (tid >= off) t = tmp[tid - off];
        __syncthreads();
        tmp[tid] += t;
        __syncthreads();
    }
    int run = tmp[tid] - s;
    for (int j = 0; j < 4; j++) {
        int idx = base + j;
        if (idx < n) rowptr[idx] = run;
        run += v[j];
    }
    if (tid == 255) partials[chunk] = tmp[255];
}

__global__ void k_scan_partials(int* __restrict__ partials, int m) {
    __shared__ int tmp[256];
    int tid = threadIdx.x;
    int s = (tid < m) ? partials[tid] : 0;
    tmp[tid] = s;
    __syncthreads();
    for (int off = 1; off < 256; off <<= 1) {
        int t = 0;
        if (tid >= off) t = tmp[tid - off];
        __syncthreads();
        tmp[tid] += t;
        __syncthreads();
    }
    if (tid < m) partials[tid] = tmp[tid] - s;
}

__global__ void k_scan_add(int* __restrict__ rowptr, const int* __restrict__ partials,
                           int* __restrict__ cursor, int n, int E) {
    int i = blockIdx.x * 256 + threadIdx.x;
    if (i < n) {
        int r = rowptr[i] + partials[i / 1024];
        rowptr[i] = r;
        cursor[i] = r;
    }
    if (i == n) rowptr[n] = E;
}

__global__ void k_scatter(const int* __restrict__ src, const int* __restrict__ dst,
                          const float* __restrict__ ew, int* __restrict__ cursor,
                          int2* __restrict__ edata, int E) {
    int i = blockIdx.x * 256 + threadIdx.x;
    if (i < E) {
        int d = dst[i];
        int p = atomicAdd(&cursor[d], 1);
        edata[p] = make_int2(src[i], __float_as_int(ew[i]));
    }
}

// ---------------- GEMM: H[n x 128](fp16) = X[n x 128] @ W[128 x 128] ----------------
// 256 threads; tile 64 rows x 64 cols (blockIdx.y = col half). f32 math in LDS.
template<bool XF16>
__global__ __launch_bounds__(256) void k_gemm(const void* __restrict__ Xv,
                                              const float* __restrict__ W,
                                              _Float16* __restrict__ H, int n) {
    __shared__ float sW[128][64];   // sW[k][c]
    __shared__ float sX[128][64];   // sX[k][r]
    int rows0 = blockIdx.x * 64;
    int cols0 = blockIdx.y * 64;
    int tid = threadIdx.x;

    for (int i = 0; i < 8; i++) {
        int L4 = i * 256 + tid;
        int k  = L4 >> 4;
        int c4 = L4 & 15;
        float4 w4 = *(const float4*)&W[k * 128 + cols0 + c4 * 4];
        *(float4*)&sW[k][c4 * 4] = w4;
    }
    {
        int r  = tid >> 2;
        int kq = (tid & 3) * 32;
        int rg = rows0 + r;
        if (XF16) {
            const _Float16* Xh = (const _Float16*)Xv + (size_t)rg * 128;
            for (int j = 0; j < 4; j++) {
                half8n v = half8n(0);
                if (rg < n) v = *(const half8n*)(Xh + kq + j * 8);
                int kk = kq + j * 8;
                #pragma unroll
                for (int q = 0; q < 8; q++) sX[kk + q][r] = (float)v[q];
            }
        } else {
            const float* Xf = (const float*)Xv + (size_t)rg * 128;
            for (int j = 0; j < 8; j++) {
                float4 xv = make_float4(0.f, 0.f, 0.f, 0.f);
                if (rg < n) xv = *(const float4*)(Xf + kq + j * 4);
                int kk = kq + j * 4;
                sX[kk + 0][r] = xv.x;
                sX[kk + 1][r] = xv.y;
                sX[kk + 2][r] = xv.z;
                sX[kk + 3][r] = xv.w;
            }
        }
    }
    __syncthreads();

    int tx = tid & 15;
    int ty = tid >> 4;
    float acc[4][4] = {};
    #pragma unroll 8
    for (int k = 0; k < 128; k++) {
        float4 a = *(const float4*)&sX[k][ty * 4];
        float4 b = *(const float4*)&sW[k][tx * 4];
        acc[0][0] += a.x * b.x; acc[0][1] += a.x * b.y; acc[0][2] += a.x * b.z; acc[0][3] += a.x * b.w;
        acc[1][0] += a.y * b.x; acc[1][1] += a.y * b.y; acc[1][2] += a.y * b.z; acc[1][3] += a.y * b.w;
        acc[2][0] += a.z * b.x; acc[2][1] += a.z * b.y; acc[2][2] += a.z * b.z; acc[2][3] += a.z * b.w;
        acc[3][0] += a.w * b.x; acc[3][1] += a.w * b.y; acc[3][2] += a.w * b.z; acc[3][3] += a.w * b.w;
    }
    for (int i = 0; i < 4; i++) {
        int row = rows0 + ty * 4 + i;
        if (row < n) {
            half4n o;
            o[0] = (_Float16)acc[i][0]; o[1] = (_Float16)acc[i][1];
            o[2] = (_Float16)acc[i][2]; o[3] = (_Float16)acc[i][3];
            *(half4n*)&H[(size_t)row * 128 + cols0 + tx * 4] = o;
        }
    }
}

// ---------------- Aggregation: out[n] = tanh(sum_e w_e * H[src_e]) ----------------
// One wave per node. 16 lanes cover the 256B fp16 row (16B/lane);
// 4 lane-groups process 4 edges concurrently; shfl_xor(16/32) combines.
template<bool OUTF16>
__global__ __launch_bounds__(256) void k_agg(const _Float16* __restrict__ H,
                                             const int* __restrict__ rowptr,
                                             const int2* __restrict__ edata,
                                             void* __restrict__ outv, int n) {
    int wid  = (blockIdx.x * 256 + threadIdx.x) >> 6;
    int lane = threadIdx.x & 63;
    if (wid >= n) return;
    int g = lane >> 4;        // edge slot 0..3
    int c = lane & 15;        // columns c*8 .. c*8+7
    int e0 = rowptr[wid], e1 = rowptr[wid + 1];
    float acc[8] = {};
    #pragma unroll 2
    for (int eb = e0; eb < e1; eb += 4) {
        int e  = eb + g;
        int ec = (e < e1) ? e : (e1 - 1);        // clamp (branchless; e1>e0 here)
        int2 ed = edata[ec];
        float w = (e < e1) ? __int_as_float(ed.y) : 0.f;
        half8n v = *(const half8n*)(H + (size_t)ed.x * 128 + c * 8);
        #pragma unroll
        for (int j = 0; j < 8; j++) acc[j] += w * (float)v[j];
    }
    float t[8];
    #pragma unroll
    for (int j = 0; j < 8; j++) {
        float a = acc[j];
        a += __shfl_xor(a, 16, 64);
        a += __shfl_xor(a, 32, 64);
        t[j] = tanhf(a);
    }
    if (OUTF16) {
        if (g == 0) {
            half8n hv;
            #pragma unroll
            for (int j = 0; j < 8; j++) hv[j] = (_Float16)t[j];
            uint4n o = *(uint4n*)&hv;
            __builtin_nontemporal_store(o, (uint4n*)((_Float16*)outv + (size_t)wid * 128 + c * 8));
        }
    } else {
        if (g < 2) {
            float4n o;
            o.x = t[g * 4 + 0]; o.y = t[g * 4 + 1];
            o.z = t[g * 4 + 2]; o.w = t[g * 4 + 3];
            __builtin_nontemporal_store(o, (float4n*)((float*)outv + (size_t)wid * 128 + c * 8 + g * 4));
        }
    }
}

// ---------------- launch ----------------

extern "C" void kernel_launch(void* const* d_in, const int* in_sizes, int n_in,
                              void* d_out, int out_size, void* d_ws, size_t ws_size,
                              hipStream_t stream) {
    const float* x    = (const float*)d_in[0];
    const int*   esrc = (const int*)d_in[1];
    const int*   edst = (const int*)d_in[2];
    const float* ew   = (const float*)d_in[3];
    const float* W1   = (const float*)d_in[4];
    const float* W2   = (const float*)d_in[5];
    float* out = (float*)d_out;

    // Workspace layout (~64.8 MB):
    _Float16* hbuf = (_Float16*)d_ws;                      // N*D fp16 (25.6 MB)
    _Float16* act1 = hbuf + (size_t)N_NODES * D;           // N*D fp16 (25.6 MB)
    int2*  edata    = (int2*)(act1 + (size_t)N_NODES * D); // E int2 (12.8 MB), 8B-aligned
    int*   deg      = (int*)(edata + N_EDGES);             // N ints (reused as cursor)
    int*   rowptr   = deg + N_NODES;                       // N+1 ints
    int*   partials = rowptr + (N_NODES + 2);              // 256 ints
    (void)ws_size; (void)in_sizes; (void)n_in; (void)out_size;

    // --- CSR build (graph identical for both layers) ---
    k_zero<<<(N_NODES + 255) / 256, 256, 0, stream>>>(deg, N_NODES);
    k_hist<<<(N_EDGES + 255) / 256, 256, 0, stream>>>(edst, deg, N_EDGES);
    int nchunk = (N_NODES + 1023) / 1024;  // 98
    k_scan_blocks<<<nchunk, 256, 0, stream>>>(deg, rowptr, partials, N_NODES);
    k_scan_partials<<<1, 256, 0, stream>>>(partials, nchunk);
    k_scan_add<<<(N_NODES + 1 + 255) / 256, 256, 0, stream>>>(rowptr, partials, deg, N_NODES, N_EDGES);
    k_scatter<<<(N_EDGES + 255) / 256, 256, 0, stream>>>(esrc, edst, ew, deg, edata, N_EDGES);

    dim3 gg((N_NODES + 63) / 64, 2);
    int agg_blocks = (N_NODES * 64 + 255) / 256;  // one wave per node

    // --- layer 1 ---
    k_gemm<false><<<gg, 256, 0, stream>>>(x, W1, hbuf, N_NODES);
    k_agg<true><<<agg_blocks, 256, 0, stream>>>(hbuf, rowptr, edata, act1, N_NODES);
    // --- layer 2 ---
    k_gemm<true><<<gg, 256, 0, stream>>>(act1, W2, hbuf, N_NODES);
    k_agg<false><<<agg_blocks, 256, 0, stream>>>(hbuf, rowptr, edata, out, N_NODES);
}